// Round 10
// baseline (346.025 us; speedup 1.0000x reference)
//
#include <hip/hip_runtime.h>
#include <hip/hip_bf16.h>
#include <stdint.h>

// ---------------------------------------------------------------------------
// CapsuleLayerSemantic: LN -> per-adapter (W1,relu,W2) -> capsule squash over A
// B=16 S=2048 NX=1024 A=20 H=50 O=3.  M = 32768 tokens.
// R17: R16 + occupancy bump on the gemm: LDS 36448 -> 32768 exactly
//     (epilogue hm[64][133] -> skewed hm[64][128], col' = (c + 5*row) & 127,
//     <=2-way banks both sides; w2s dropped from LDS -- W2 is 12KB L1/L2-hot,
//     read direct in the dot loop) => 5 blocks/CU (was 4). K-loop, staging,
//     swizzle, grid, pre, squash byte-identical to R16 (gemm 94.4us, 33%).
// ---------------------------------------------------------------------------

typedef _Float16 h8 __attribute__((ext_vector_type(8)));
typedef float f4 __attribute__((ext_vector_type(4)));
typedef __attribute__((address_space(1))) void gvoid;
typedef __attribute__((address_space(3))) void lvoid;

__device__ __forceinline__ void cp16(const void* g, void* l) {
  __builtin_amdgcn_global_load_lds((gvoid*)g, (lvoid*)l, 16, 0, 0);
}

// ---------------- kernel 1: prep (432 blocks) + layernorm (8192 blocks) -----
// blocks [0,320): (a = b/16, ky = b%16): W1*ln_g transpose -> packed wB fp16,
//   exact off partial for this k-chunk -> offpart[ky][a*50+h].
//   a==0 blocks also zero wB pad rows 1000..1023 for their k-chunk.
// blocks [320,432): zero out-slices of the 7 boundary-split adapters
//   {2,5,7,10,12,15,17} (gemm nb=128-wide; those slices get atomicAdd).
// blocks [432,8624): LN + fp16 cast, one wave per token (unit-stride).
__global__ __launch_bounds__(256) void pre_kernel(
    const float* __restrict__ x, const float* __restrict__ ln_g,
    const float* __restrict__ ln_b, const float* __restrict__ W1,
    _Float16* __restrict__ wB, float* __restrict__ offpart,
    float* __restrict__ out, _Float16* __restrict__ xn) {
  const int t = threadIdx.x;
  if (blockIdx.x >= 432) {  // ---------------- LN path ----------------
    const int w = t >> 6, l = t & 63;
    const int tok = (blockIdx.x - 432) * 4 + w;
    const float4* xr = (const float4*)(x + (size_t)tok * 1024);
    float4 v0 = xr[l], v1 = xr[64 + l], v2 = xr[128 + l], v3 = xr[192 + l];
    float s1 = (v0.x + v0.y + v0.z + v0.w) + (v1.x + v1.y + v1.z + v1.w) +
               (v2.x + v2.y + v2.z + v2.w) + (v3.x + v3.y + v3.z + v3.w);
    float s2 = v0.x * v0.x + v0.y * v0.y + v0.z * v0.z + v0.w * v0.w;
    s2 += v1.x * v1.x + v1.y * v1.y + v1.z * v1.z + v1.w * v1.w;
    s2 += v2.x * v2.x + v2.y * v2.y + v2.z * v2.z + v2.w * v2.w;
    s2 += v3.x * v3.x + v3.y * v3.y + v3.z * v3.z + v3.w * v3.w;
#pragma unroll
    for (int m = 32; m > 0; m >>= 1) {
      s1 += __shfl_xor(s1, m);
      s2 += __shfl_xor(s2, m);
    }
    const float mu = s1 * 0.0009765625f;
    const float var = s2 * 0.0009765625f - mu * mu;
    const float inv = rsqrtf(var + 1e-5f);
    uint2* xw = (uint2*)(xn + (size_t)tok * 1024);
    union { _Float16 h[4]; uint2 u; } q;
#define CVT_STORE(V, OFF)                                 \
    q.h[0] = (_Float16)((V.x - mu) * inv);                \
    q.h[1] = (_Float16)((V.y - mu) * inv);                \
    q.h[2] = (_Float16)((V.z - mu) * inv);                \
    q.h[3] = (_Float16)((V.w - mu) * inv);                \
    xw[(OFF) + l] = q.u;
    CVT_STORE(v0, 0)
    CVT_STORE(v1, 64)
    CVT_STORE(v2, 128)
    CVT_STORE(v3, 192)
#undef CVT_STORE
    return;
  }
  if (blockIdx.x >= 320) {  // ---------------- out-slice zeroing ----------
    static const int sa[7] = {2, 5, 7, 10, 12, 15, 17};
    const int idx = blockIdx.x - 320;        // 0..111
    const int ai = idx >> 4, bi = idx & 15;  // adapter-slot, batch
    float4* dst = (float4*)(out + ((size_t)(bi * 20 + sa[ai])) * 6144);
    const float4 z4 = {0.f, 0.f, 0.f, 0.f};
    for (int i = t; i < 1536; i += 256) dst[i] = z4;
    return;
  }
  // ---------------- prep path ----------------
  const int a = blockIdx.x >> 4, k0 = (blockIdx.x & 15) * 64;
  __shared__ float tw[3200];  // W1[a][k0..k0+64][0..50]
  __shared__ float gg[64], bb[64], red[256];
  const float* src = W1 + (size_t)(a * 1024 + k0) * 50;
  for (int i = t; i < 3200; i += 256) tw[i] = src[i];
  if (t < 64) gg[t] = ln_g[a * 1024 + k0 + t];
  else if (t < 128) bb[t - 64] = ln_b[a * 1024 + k0 + (t - 64)];
  __syncthreads();
  const int h = t & 63, q = t >> 6;
  float po = 0.f;
  if (h < 50) {
#pragma unroll
    for (int half = 0; half < 2; ++half) {
      union { _Float16 hh[8]; uint4 u; } pk;
#pragma unroll
      for (int j = 0; j < 8; ++j) {
        const int k = q * 16 + half * 8 + j;
        const float wv = tw[k * 50 + h];
        pk.hh[j] = (_Float16)(gg[k] * wv);
        po += bb[k] * wv;
      }
      *(uint4*)(wB + (size_t)(a * 50 + h) * 1024 + k0 + q * 16 + half * 8) =
          pk.u;
    }
  }
  red[t] = po;
  __syncthreads();
  if (t < 50)
    offpart[(blockIdx.x & 15) * 1024 + a * 50 + t] =
        red[t] + red[64 + t] + red[128 + t] + red[192 + t];
  if (a == 0 && t < 192) {  // zero wB pad rows 1000..1023 for this k-chunk
    const uint4 z = {0, 0, 0, 0};
    *(uint4*)(wB + (size_t)(1000 + (t >> 3)) * 1024 + k0 + (t & 7) * 8) = z;
  }
}

// ---------------- kernel 2: GEMM + partial-adapter epilogue -----------------
// R7-proven core: 1D grid 2048, swizzled: xcd=g&7, i=g>>3, nb=i&7,
// mb=xcd*32+(i>>3). 128x128 tile, BK=64, mfma_f32_16x16x32_f16, 4 waves 2x2,
// XOR-swizzled LDS, A/B via global_load_lds width-16.
// R17: LDS exactly 32768 -> 5 blocks/CU. Epilogue hm is [64][128] with skew
// col' = (c + 5*row) & 127 (<=2-way banks both sides; 4-lane j-groups still
// broadcast). W2 read direct from global (12KB, L1/L2-hot) in the dot loop.
__global__ __launch_bounds__(256, 5) void gemm_kernel(
    const _Float16* __restrict__ xn, const _Float16* __restrict__ wB,
    const float* __restrict__ offpart, const float* __restrict__ b1,
    const float* __restrict__ W2, float* __restrict__ out) {
  __shared__ __align__(16) char smem[32768];
  // [0,16384) sA | [16384,32768) sB | epilogue reuse: hm[64][128] skewed
  const int g = blockIdx.x;
  const int xcd = g & 7, i0 = g >> 3;
  const int nb = i0 & 7;
  const int mb = xcd * 32 + (i0 >> 3);
  const int t = threadIdx.x, w = t >> 6, l = t & 63;

  const int a0 = (nb * 128) / 50;

  // staging: chunk = 8 rows (1KB); lane -> row chunk*8+(l>>3), phys slot l&7
  // holding logical k-slot (l&7)^(l>>3).
  const int lr = l >> 3;
  const int ksl = (l & 7) ^ lr;
  const _Float16* gA = xn + (size_t)(mb * 128 + lr) * 1024 + ksl * 8;
  const _Float16* gB = wB + (size_t)(nb * 128 + lr) * 1024 + ksl * 8;

  const int rowA = ((w >> 1) * 64) + (l & 15);
  const int rowB = ((w & 1) * 64) + (l & 15);
  const int kq = l >> 4;
  const int xa = rowA & 7, xb = rowB & 7;
  const char* pA = smem + rowA * 128;
  const char* pB = smem + 16384 + rowB * 128;

  f4 acc[4][4];
  {
    f4 z = {0.f, 0.f, 0.f, 0.f};
#pragma unroll
    for (int mt = 0; mt < 4; ++mt)
#pragma unroll
      for (int nt = 0; nt < 4; ++nt) acc[mt][nt] = z;
  }

  for (int kt = 0; kt < 16; ++kt) {
#pragma unroll
    for (int i = 0; i < 4; ++i) {
      const int chunk = w * 4 + i;
      cp16(gA + (size_t)chunk * 8192 + kt * 64, smem + chunk * 1024);
      cp16(gB + (size_t)chunk * 8192 + kt * 64, smem + 16384 + chunk * 1024);
    }
    __syncthreads();
#pragma unroll
    for (int ks = 0; ks < 2; ++ks) {
      h8 af[4], bf[4];
      const int sl = ks * 4 + kq;
#pragma unroll
      for (int mt = 0; mt < 4; ++mt)
        af[mt] = *(const h8*)(pA + mt * 2048 + ((sl ^ xa) << 4));
#pragma unroll
      for (int nt = 0; nt < 4; ++nt)
        bf[nt] = *(const h8*)(pB + nt * 2048 + ((sl ^ xb) << 4));
#pragma unroll
      for (int mt = 0; mt < 4; ++mt)
#pragma unroll
        for (int nt = 0; nt < 4; ++nt)
          acc[mt][nt] = __builtin_amdgcn_mfma_f32_16x16x32_f16(
              af[mt], bf[nt], acc[mt][nt], 0, 0, 0);
    }
    __syncthreads();
  }

  // off_total[nt] = b1[n] + sum_{c<16} offpart[c][n]  (4KB tables, L2-hot)
  float offt[4];
  int ncols[4];
#pragma unroll
  for (int nt = 0; nt < 4; ++nt) {
    ncols[nt] = nb * 128 + rowB + nt * 16;
    offt[nt] = (ncols[nt] < 1000) ? b1[ncols[nt]] : 0.f;
  }
#pragma unroll
  for (int c = 0; c < 16; ++c)
#pragma unroll
    for (int nt = 0; nt < 4; ++nt) offt[nt] += offpart[c * 1024 + ncols[nt]];

  // per-thread dot assignment: 64 tokens x 4 adapter slots
  const int ml = t >> 2, j = t & 3;
  const int a = a0 + j;
  const int c0 = nb * 128;
  int cs = a * 50, ce = cs + 50;
  if (cs < c0) cs = c0;
  if (ce > c0 + 128) ce = c0 + 128;
  const bool act = (a < 20) && (cs < ce);
  const int lo = cs - c0;
  const int len = act ? (ce - cs) : 0;
  const int h0 = cs - a * 50;
  const float* wrow = W2 + a * 150 + h0 * 3;  // global, L1/L2-hot (12KB total)

  float* hm = (float*)smem;  // [64][128], skew col' = (c + 5*row) & 127
  const int mrl = (l >> 4) * 4;
  const int ncol = (w & 1) * 64 + (l & 15);
#pragma unroll
  for (int p = 0; p < 2; ++p) {
    if (p) __syncthreads();
    if ((w >> 1) == p) {
#pragma unroll
      for (int mt = 0; mt < 4; ++mt)
#pragma unroll
        for (int nt = 0; nt < 4; ++nt)
#pragma unroll
          for (int r = 0; r < 4; ++r) {
            const int row = mrl + mt * 16 + r;
            hm[row * 128 + ((ncol + nt * 16 + 5 * row) & 127)] =
                fmaxf(acc[mt][nt][r] + offt[nt], 0.f);
          }
    }
    __syncthreads();
    if (act) {
      const int rbase = ml * 128;
      const int sk = lo + 5 * ml;
      float o0 = 0.f, o1 = 0.f, o2 = 0.f;
      for (int i = 0; i < len; ++i) {
        const float hv = hm[rbase + ((sk + i) & 127)];
        o0 += hv * wrow[i * 3 + 0];
        o1 += hv * wrow[i * 3 + 1];
        o2 += hv * wrow[i * 3 + 2];
      }
      const int tok = mb * 128 + p * 64 + ml;
      const int b = tok >> 11, s = tok & 2047;
      float* op = out + ((size_t)(b * 20 + a) * 2048 + (size_t)s) * 3;
      if (len == 50) {  // adapter fully inside this nb block: direct store
        op[0] = o0; op[1] = o1; op[2] = o2;
      } else {          // boundary-split adapter: slice was pre-zeroed
        atomicAdd(op + 0, o0);
        atomicAdd(op + 1, o1);
        atomicAdd(op + 2, o2);
      }
    }
  }
}

// ---------------- kernel 3: +b2, capsule squash over A, float4 --------------
// idx over float4s: 16 batches x 1536 float4 (6144 floats). Per-component
// output index oi = element % 3.
__global__ __launch_bounds__(256) void squash_kernel(
    float* __restrict__ out, const float* __restrict__ b2) {
  const int idx = blockIdx.x * 256 + threadIdx.x;  // 0 .. 16*1536-1
  const int b = idx / 1536;
  const int r4 = idx - b * 1536;
  const int e0 = r4 * 4;
  const int oi0 = e0 % 3;                 // oi pattern: oi0, +1, +2, oi0
  const int oi1 = (oi0 + 1) % 3, oi2 = (oi0 + 2) % 3;
  float4 v[20];
  float4 sq = {0.f, 0.f, 0.f, 0.f};
#pragma unroll
  for (int a = 0; a < 20; ++a) {
    float4 t = *(const float4*)(out + ((size_t)(b * 20 + a)) * 6144 + e0);
    t.x += b2[a * 3 + oi0];
    t.y += b2[a * 3 + oi1];
    t.z += b2[a * 3 + oi2];
    t.w += b2[a * 3 + oi0];
    v[a] = t;
    sq.x += t.x * t.x;
    sq.y += t.y * t.y;
    sq.z += t.z * t.z;
    sq.w += t.w * t.w;
  }
  float4 f;
  f.x = sqrtf(sq.x) / (1.f + sq.x);  // (sq/(1+sq))*rsqrt(sq), safe at 0
  f.y = sqrtf(sq.y) / (1.f + sq.y);
  f.z = sqrtf(sq.z) / (1.f + sq.z);
  f.w = sqrtf(sq.w) / (1.f + sq.w);
#pragma unroll
  for (int a = 0; a < 20; ++a) {
    float4 t = v[a];
    t.x *= f.x; t.y *= f.y; t.z *= f.z; t.w *= f.w;
    *(float4*)(out + ((size_t)(b * 20 + a)) * 6144 + e0) = t;
  }
}

// ---------------------------------------------------------------------------
extern "C" void kernel_launch(void* const* d_in, const int* in_sizes, int n_in,
                              void* d_out, int out_size, void* d_ws,
                              size_t ws_size, hipStream_t stream) {
  const float* x    = (const float*)d_in[0];  // [16,2048,1024]
  const float* ln_g = (const float*)d_in[1];  // [20,1024]
  const float* ln_b = (const float*)d_in[2];  // [20,1024]
  const float* W1   = (const float*)d_in[3];  // [20,1024,50]
  const float* b1   = (const float*)d_in[4];  // [20,50]
  const float* W2   = (const float*)d_in[5];  // [20,50,3]
  const float* b2   = (const float*)d_in[6];  // [20,3]
  float* out = (float*)d_out;                 // [16,20,6144]

  char* ws = (char*)d_ws;
  float* offpart = (float*)ws;                        // [16][1024] f32 (64KB)
  _Float16* wBw  = (_Float16*)(ws + 65536);           // 1024*1024 fp16 (2MB)
  _Float16* xnw  = (_Float16*)(ws + 65536 + 2097152); // 32768*1024 fp16 (67MB)

  pre_kernel<<<8624, 256, 0, stream>>>(x, ln_g, ln_b, W1, wBw, offpart, out,
                                       xnw);
  gemm_kernel<<<2048, 256, 0, stream>>>(xnw, wBw, offpart, b1, W2, out);
  squash_kernel<<<96, 256, 0, stream>>>(out, b2);
}

// Round 11
// 299.288 us; speedup vs baseline: 1.1562x; 1.1562x over previous
//
#include <hip/hip_runtime.h>
#include <hip/hip_bf16.h>
#include <stdint.h>

// ---------------------------------------------------------------------------
// CapsuleLayerSemantic: LN -> per-adapter (W1,relu,W2) -> capsule squash over A
// B=16 S=2048 NX=1024 A=20 H=50 O=3.  M = 32768 tokens.
// R18 = R16/R13 final resubmission (verified best: 302.7us / 304.3us).
// Session record (17 variants):
//   - 8-phase 256^2 ports (R8-R12): ~100us gemm / 28% MfmaUtil; asm-read,
//     sched_barrier, and clobber theories all falsified single-variable.
//   - fused squash (R14): +55us (cross-XCD out re-read tail) -> reverted.
//   - 2-phase BK=32 dbuf (R15): 110us (short compute phase exposes staging
//     latency) -> reverted.
//   - 5 blk/CU (R17): 143us — unified VGPR+AGPR budget 512/5=102 < 124
//     needed -> acc spills to scratch (WRITE 21->58MB). Register-limited to
//     4 waves/SIMD regardless of LDS; lever impossible.
// Final: R7 gemm (stage -> sync -> 2x16 MFMA -> sync, 4 blk/CU, XCD-swizzle,
// XOR-LDS, global_load_lds w16): 91.5us, MfmaUtil 33% — schedule-bound
// structural ceiling for this loop shape. pre = prep+zero+LN one dispatch;
// squash = float4.
// ---------------------------------------------------------------------------

typedef _Float16 h8 __attribute__((ext_vector_type(8)));
typedef float f4 __attribute__((ext_vector_type(4)));
typedef __attribute__((address_space(1))) void gvoid;
typedef __attribute__((address_space(3))) void lvoid;

__device__ __forceinline__ void cp16(const void* g, void* l) {
  __builtin_amdgcn_global_load_lds((gvoid*)g, (lvoid*)l, 16, 0, 0);
}

// ---------------- kernel 1: prep (432 blocks) + layernorm (8192 blocks) -----
// blocks [0,320): (a = b/16, ky = b%16): W1*ln_g transpose -> packed wB fp16,
//   exact off partial for this k-chunk -> offpart[ky][a*50+h].
//   a==0 blocks also zero wB pad rows 1000..1023 for their k-chunk.
// blocks [320,432): zero out-slices of the 7 boundary-split adapters
//   {2,5,7,10,12,15,17} (gemm nb=128-wide; those slices get atomicAdd).
// blocks [432,8624): LN + fp16 cast, one wave per token (unit-stride).
__global__ __launch_bounds__(256) void pre_kernel(
    const float* __restrict__ x, const float* __restrict__ ln_g,
    const float* __restrict__ ln_b, const float* __restrict__ W1,
    _Float16* __restrict__ wB, float* __restrict__ offpart,
    float* __restrict__ out, _Float16* __restrict__ xn) {
  const int t = threadIdx.x;
  if (blockIdx.x >= 432) {  // ---------------- LN path ----------------
    const int w = t >> 6, l = t & 63;
    const int tok = (blockIdx.x - 432) * 4 + w;
    const float4* xr = (const float4*)(x + (size_t)tok * 1024);
    float4 v0 = xr[l], v1 = xr[64 + l], v2 = xr[128 + l], v3 = xr[192 + l];
    float s1 = (v0.x + v0.y + v0.z + v0.w) + (v1.x + v1.y + v1.z + v1.w) +
               (v2.x + v2.y + v2.z + v2.w) + (v3.x + v3.y + v3.z + v3.w);
    float s2 = v0.x * v0.x + v0.y * v0.y + v0.z * v0.z + v0.w * v0.w;
    s2 += v1.x * v1.x + v1.y * v1.y + v1.z * v1.z + v1.w * v1.w;
    s2 += v2.x * v2.x + v2.y * v2.y + v2.z * v2.z + v2.w * v2.w;
    s2 += v3.x * v3.x + v3.y * v3.y + v3.z * v3.z + v3.w * v3.w;
#pragma unroll
    for (int m = 32; m > 0; m >>= 1) {
      s1 += __shfl_xor(s1, m);
      s2 += __shfl_xor(s2, m);
    }
    const float mu = s1 * 0.0009765625f;
    const float var = s2 * 0.0009765625f - mu * mu;
    const float inv = rsqrtf(var + 1e-5f);
    uint2* xw = (uint2*)(xn + (size_t)tok * 1024);
    union { _Float16 h[4]; uint2 u; } q;
#define CVT_STORE(V, OFF)                                 \
    q.h[0] = (_Float16)((V.x - mu) * inv);                \
    q.h[1] = (_Float16)((V.y - mu) * inv);                \
    q.h[2] = (_Float16)((V.z - mu) * inv);                \
    q.h[3] = (_Float16)((V.w - mu) * inv);                \
    xw[(OFF) + l] = q.u;
    CVT_STORE(v0, 0)
    CVT_STORE(v1, 64)
    CVT_STORE(v2, 128)
    CVT_STORE(v3, 192)
#undef CVT_STORE
    return;
  }
  if (blockIdx.x >= 320) {  // ---------------- out-slice zeroing ----------
    static const int sa[7] = {2, 5, 7, 10, 12, 15, 17};
    const int idx = blockIdx.x - 320;        // 0..111
    const int ai = idx >> 4, bi = idx & 15;  // adapter-slot, batch
    float4* dst = (float4*)(out + ((size_t)(bi * 20 + sa[ai])) * 6144);
    const float4 z4 = {0.f, 0.f, 0.f, 0.f};
    for (int i = t; i < 1536; i += 256) dst[i] = z4;
    return;
  }
  // ---------------- prep path ----------------
  const int a = blockIdx.x >> 4, k0 = (blockIdx.x & 15) * 64;
  __shared__ float tw[3200];  // W1[a][k0..k0+64][0..50]
  __shared__ float gg[64], bb[64], red[256];
  const float* src = W1 + (size_t)(a * 1024 + k0) * 50;
  for (int i = t; i < 3200; i += 256) tw[i] = src[i];
  if (t < 64) gg[t] = ln_g[a * 1024 + k0 + t];
  else if (t < 128) bb[t - 64] = ln_b[a * 1024 + k0 + (t - 64)];
  __syncthreads();
  const int h = t & 63, q = t >> 6;
  float po = 0.f;
  if (h < 50) {
#pragma unroll
    for (int half = 0; half < 2; ++half) {
      union { _Float16 hh[8]; uint4 u; } pk;
#pragma unroll
      for (int j = 0; j < 8; ++j) {
        const int k = q * 16 + half * 8 + j;
        const float wv = tw[k * 50 + h];
        pk.hh[j] = (_Float16)(gg[k] * wv);
        po += bb[k] * wv;
      }
      *(uint4*)(wB + (size_t)(a * 50 + h) * 1024 + k0 + q * 16 + half * 8) =
          pk.u;
    }
  }
  red[t] = po;
  __syncthreads();
  if (t < 50)
    offpart[(blockIdx.x & 15) * 1024 + a * 50 + t] =
        red[t] + red[64 + t] + red[128 + t] + red[192 + t];
  if (a == 0 && t < 192) {  // zero wB pad rows 1000..1023 for this k-chunk
    const uint4 z = {0, 0, 0, 0};
    *(uint4*)(wB + (size_t)(1000 + (t >> 3)) * 1024 + k0 + (t & 7) * 8) = z;
  }
}

// ---------------- kernel 2: GEMM + partial-adapter epilogue (R7, proven) ----
// 1D grid 2048, swizzled: xcd=g&7, i=g>>3, nb=i&7, mb=xcd*32+(i>>3) — each
// XCD walks all 8 nb for one mb, so the A-tile is fetched into L2 once per mb
// and wB (2MB) stays L2-resident. 128x128 tile, BK=64,
// mfma_f32_16x16x32_f16, 4 waves 2x2, XOR-swizzled LDS, A/B via
// global_load_lds width-16. Epilogue: full adapters direct-store; boundary-
// split adapters atomicAdd onto pre-zeroed slices.
__global__ __launch_bounds__(256, 4) void gemm_kernel(
    const _Float16* __restrict__ xn, const _Float16* __restrict__ wB,
    const float* __restrict__ offpart, const float* __restrict__ b1,
    const float* __restrict__ W2, float* __restrict__ out) {
  __shared__ __align__(16) char smem[36448];
  // [0,16384) sA | [16384,32768) sB | reuse: hm=float[64][133]=34048
  // [34048,36448) w2s: 600 f32 (W2 for adapters a0..a0+3)
  const int g = blockIdx.x;
  const int xcd = g & 7, i0 = g >> 3;
  const int nb = i0 & 7;
  const int mb = xcd * 32 + (i0 >> 3);
  const int t = threadIdx.x, w = t >> 6, l = t & 63;

  const int a0 = (nb * 128) / 50;
  float* w2s = (float*)(smem + 34048);
  for (int i = t; i < 600; i += 256) {
    const int j = i / 150, a = a0 + j;
    w2s[i] = (a < 20) ? W2[a * 150 + (i - j * 150)] : 0.f;
  }

  // staging: chunk = 8 rows (1KB); lane -> row chunk*8+(l>>3), phys slot l&7
  // holding logical k-slot (l&7)^(l>>3).
  const int lr = l >> 3;
  const int ksl = (l & 7) ^ lr;
  const _Float16* gA = xn + (size_t)(mb * 128 + lr) * 1024 + ksl * 8;
  const _Float16* gB = wB + (size_t)(nb * 128 + lr) * 1024 + ksl * 8;

  const int rowA = ((w >> 1) * 64) + (l & 15);
  const int rowB = ((w & 1) * 64) + (l & 15);
  const int kq = l >> 4;
  const int xa = rowA & 7, xb = rowB & 7;
  const char* pA = smem + rowA * 128;
  const char* pB = smem + 16384 + rowB * 128;

  f4 acc[4][4];
  {
    f4 z = {0.f, 0.f, 0.f, 0.f};
#pragma unroll
    for (int mt = 0; mt < 4; ++mt)
#pragma unroll
      for (int nt = 0; nt < 4; ++nt) acc[mt][nt] = z;
  }

  for (int kt = 0; kt < 16; ++kt) {
#pragma unroll
    for (int i = 0; i < 4; ++i) {
      const int chunk = w * 4 + i;
      cp16(gA + (size_t)chunk * 8192 + kt * 64, smem + chunk * 1024);
      cp16(gB + (size_t)chunk * 8192 + kt * 64, smem + 16384 + chunk * 1024);
    }
    __syncthreads();
#pragma unroll
    for (int ks = 0; ks < 2; ++ks) {
      h8 af[4], bf[4];
      const int sl = ks * 4 + kq;
#pragma unroll
      for (int mt = 0; mt < 4; ++mt)
        af[mt] = *(const h8*)(pA + mt * 2048 + ((sl ^ xa) << 4));
#pragma unroll
      for (int nt = 0; nt < 4; ++nt)
        bf[nt] = *(const h8*)(pB + nt * 2048 + ((sl ^ xb) << 4));
#pragma unroll
      for (int mt = 0; mt < 4; ++mt)
#pragma unroll
        for (int nt = 0; nt < 4; ++nt)
          acc[mt][nt] = __builtin_amdgcn_mfma_f32_16x16x32_f16(
              af[mt], bf[nt], acc[mt][nt], 0, 0, 0);
    }
    __syncthreads();
  }

  // off_total[nt] = b1[n] + sum_{c<16} offpart[c][n]  (4KB tables, L2-hot)
  float offt[4];
  int ncols[4];
#pragma unroll
  for (int nt = 0; nt < 4; ++nt) {
    ncols[nt] = nb * 128 + rowB + nt * 16;
    offt[nt] = (ncols[nt] < 1000) ? b1[ncols[nt]] : 0.f;
  }
#pragma unroll
  for (int c = 0; c < 16; ++c)
#pragma unroll
    for (int nt = 0; nt < 4; ++nt) offt[nt] += offpart[c * 1024 + ncols[nt]];

  // per-thread dot assignment: 64 tokens x 4 adapter slots
  const int ml = t >> 2, j = t & 3;
  const int a = a0 + j;
  const int c0 = nb * 128;
  int cs = a * 50, ce = cs + 50;
  if (cs < c0) cs = c0;
  if (ce > c0 + 128) ce = c0 + 128;
  const bool act = (a < 20) && (cs < ce);
  const int lo = cs - c0;
  const int len = act ? (ce - cs) : 0;
  const int h0 = cs - a * 50;
  const float* wrow = w2s + j * 150 + h0 * 3;

  float* hm = (float*)smem;  // [64][133]
  const int mrl = (l >> 4) * 4;
  const int ncol = (w & 1) * 64 + (l & 15);
#pragma unroll
  for (int p = 0; p < 2; ++p) {
    if (p) __syncthreads();
    if ((w >> 1) == p) {
#pragma unroll
      for (int mt = 0; mt < 4; ++mt)
#pragma unroll
        for (int nt = 0; nt < 4; ++nt)
#pragma unroll
          for (int r = 0; r < 4; ++r)
            hm[(mrl + mt * 16 + r) * 133 + (ncol + nt * 16)] =
                fmaxf(acc[mt][nt][r] + offt[nt], 0.f);
    }
    __syncthreads();
    if (act) {
      const float* hr = hm + ml * 133 + lo;
      float o0 = 0.f, o1 = 0.f, o2 = 0.f;
      for (int i = 0; i < len; ++i) {
        const float hv = hr[i];
        o0 += hv * wrow[i * 3 + 0];
        o1 += hv * wrow[i * 3 + 1];
        o2 += hv * wrow[i * 3 + 2];
      }
      const int tok = mb * 128 + p * 64 + ml;
      const int b = tok >> 11, s = tok & 2047;
      float* op = out + ((size_t)(b * 20 + a) * 2048 + (size_t)s) * 3;
      if (len == 50) {  // adapter fully inside this nb block: direct store
        op[0] = o0; op[1] = o1; op[2] = o2;
      } else {          // boundary-split adapter: slice was pre-zeroed
        atomicAdd(op + 0, o0);
        atomicAdd(op + 1, o1);
        atomicAdd(op + 2, o2);
      }
    }
  }
}

// ---------------- kernel 3: +b2, capsule squash over A, float4 --------------
// idx over float4s: 16 batches x 1536 float4 (6144 floats). Per-component
// output index oi = element % 3.
__global__ __launch_bounds__(256) void squash_kernel(
    float* __restrict__ out, const float* __restrict__ b2) {
  const int idx = blockIdx.x * 256 + threadIdx.x;  // 0 .. 16*1536-1
  const int b = idx / 1536;
  const int r4 = idx - b * 1536;
  const int e0 = r4 * 4;
  const int oi0 = e0 % 3;                 // oi pattern: oi0, +1, +2, oi0
  const int oi1 = (oi0 + 1) % 3, oi2 = (oi0 + 2) % 3;
  float4 v[20];
  float4 sq = {0.f, 0.f, 0.f, 0.f};
#pragma unroll
  for (int a = 0; a < 20; ++a) {
    float4 t = *(const float4*)(out + ((size_t)(b * 20 + a)) * 6144 + e0);
    t.x += b2[a * 3 + oi0];
    t.y += b2[a * 3 + oi1];
    t.z += b2[a * 3 + oi2];
    t.w += b2[a * 3 + oi0];
    v[a] = t;
    sq.x += t.x * t.x;
    sq.y += t.y * t.y;
    sq.z += t.z * t.z;
    sq.w += t.w * t.w;
  }
  float4 f;
  f.x = sqrtf(sq.x) / (1.f + sq.x);  // (sq/(1+sq))*rsqrt(sq), safe at 0
  f.y = sqrtf(sq.y) / (1.f + sq.y);
  f.z = sqrtf(sq.z) / (1.f + sq.z);
  f.w = sqrtf(sq.w) / (1.f + sq.w);
#pragma unroll
  for (int a = 0; a < 20; ++a) {
    float4 t = v[a];
    t.x *= f.x; t.y *= f.y; t.z *= f.z; t.w *= f.w;
    *(float4*)(out + ((size_t)(b * 20 + a)) * 6144 + e0) = t;
  }
}

// ---------------------------------------------------------------------------
extern "C" void kernel_launch(void* const* d_in, const int* in_sizes, int n_in,
                              void* d_out, int out_size, void* d_ws,
                              size_t ws_size, hipStream_t stream) {
  const float* x    = (const float*)d_in[0];  // [16,2048,1024]
  const float* ln_g = (const float*)d_in[1];  // [20,1024]
  const float* ln_b = (const float*)d_in[2];  // [20,1024]
  const float* W1   = (const float*)d_in[3];  // [20,1024,50]
  const float* b1   = (const float*)d_in[4];  // [20,50]
  const float* W2   = (const float*)d_in[5];  // [20,50,3]
  const float* b2   = (const float*)d_in[6];  // [20,3]
  float* out = (float*)d_out;                 // [16,20,6144]

  char* ws = (char*)d_ws;
  float* offpart = (float*)ws;                        // [16][1024] f32 (64KB)
  _Float16* wBw  = (_Float16*)(ws + 65536);           // 1024*1024 fp16 (2MB)
  _Float16* xnw  = (_Float16*)(ws + 65536 + 2097152); // 32768*1024 fp16 (67MB)

  pre_kernel<<<8624, 256, 0, stream>>>(x, ln_g, ln_b, W1, wBw, offpart, out,
                                       xnw);
  gemm_kernel<<<2048, 256, 0, stream>>>(xnw, wBw, offpart, b1, W2, out);
  squash_kernel<<<96, 256, 0, stream>>>(out, b2);
}